// Round 3
// baseline (35.261 us; speedup 1.0000x reference)
//
#include <hip/hip_runtime.h>
#include <math.h>

constexpr int NB = 4;
constexpr int NN = 512;
constexpr int ND = 32;
constexpr int NPE = 16;
constexpr float INV_SQRT_D = 0.17677669529663687f; // 1/sqrt(32)
constexpr float KSHARP = 10.0f;

// ws layout: [hl: B*N*2*ND floats interleaved {h,log(h+eps)}][kwq: B*N*17 floats]
constexpr int HL_FLOATS = NB * NN * 2 * ND;   // 131072
constexpr int KWQ_STRIDE = 17;                 // 16 KWq + C0

// ---------- Prep: per-row K, KWq, C0, and packed {h, log(h+1e-8)} ----------
__global__ __launch_bounds__(256) void prep_kernel(
    const float* __restrict__ h,
    const float* __restrict__ pe,
    const float* __restrict__ Wk,
    const float* __restrict__ bk,
    const float* __restrict__ Wq,
    const float* __restrict__ bq,
    float* __restrict__ hl,
    float* __restrict__ kwq)
{
    const int wave = threadIdx.x >> 6;
    const int lane = threadIdx.x & 63;
    const int row  = blockIdx.x * 4 + wave;    // [0, B*N)
    const int d    = lane & 31;

    __shared__ float sK[4][ND];

    const float* pe_i = pe + (size_t)row * NPE;
    float k = bk[d];
    #pragma unroll
    for (int p = 0; p < NPE; ++p) k = fmaf(pe_i[p], Wk[p * ND + d], k);

    if (lane < 32) {
        sK[wave][d] = k;
        const float hv = h[(size_t)row * ND + d];
        hl[(size_t)row * 64 + 2 * d]     = hv;
        hl[(size_t)row * 64 + 2 * d + 1] = logf(hv + 1e-8f);
    }
    __syncthreads();

    if (lane < 17) {
        const float* wrow = (lane < 16) ? (Wq + lane * ND) : bq;
        float acc = 0.f;
        #pragma unroll
        for (int dd = 0; dd < ND; ++dd) acc = fmaf(sK[wave][dd], wrow[dd], acc);
        kwq[(size_t)row * KWQ_STRIDE + lane] = acc;
    }
}

// ---------- Main: one wave per output row, barrier-free critical path ----------
__global__ __launch_bounds__(256) void fpg_kernel(
    const float* __restrict__ pe,
    const float* __restrict__ E,
    const float* __restrict__ A,
    const float* __restrict__ beta,
    const float* __restrict__ hl,
    const float* __restrict__ kwq,
    float* __restrict__ out)
{
    const int wave = threadIdx.x >> 6;
    const int lane = threadIdx.x & 63;
    const int row  = blockIdx.x * 4 + wave;
    const int b    = row >> 9;
    const int i    = row & (NN - 1);
    const int d    = lane & 31;
    const int half = lane >> 5;

    __shared__ float4 sP[4][NN];   // {W, W*Ed, sig, 0} per j — 32 KB

    // per-wave uniform row data (broadcast loads)
    const float* kb = kwq + (size_t)row * KWQ_STRIDE;
    float kq[17];
    #pragma unroll
    for (int p = 0; p < 17; ++p) kq[p] = kb[p];
    const float Ei = E[i];
    const float2 hli = *(const float2*)(hl + (size_t)row * 64 + 2 * d);
    const float hi = hli.x, Li = hli.y;
    const float bd = beta[d];

    // ---- scores, E-diff, sigmoid: 8 j per lane, all in registers ----
    const float* pe_b = pe + (size_t)b * NN * NPE;
    const float* Arow = A + (size_t)i * NN;
    float sc[8], ed[8], sg[8];
    #pragma unroll
    for (int c = 0; c < 8; ++c) {
        const int j = c * 64 + lane;
        const float4* pj = (const float4*)(pe_b + (size_t)j * NPE);
        const float4 p0 = pj[0], p1 = pj[1], p2 = pj[2], p3 = pj[3];
        float dot = kq[16];
        dot = fmaf(p0.x, kq[0],  dot); dot = fmaf(p0.y, kq[1],  dot);
        dot = fmaf(p0.z, kq[2],  dot); dot = fmaf(p0.w, kq[3],  dot);
        dot = fmaf(p1.x, kq[4],  dot); dot = fmaf(p1.y, kq[5],  dot);
        dot = fmaf(p1.z, kq[6],  dot); dot = fmaf(p1.w, kq[7],  dot);
        dot = fmaf(p2.x, kq[8],  dot); dot = fmaf(p2.y, kq[9],  dot);
        dot = fmaf(p2.z, kq[10], dot); dot = fmaf(p2.w, kq[11], dot);
        dot = fmaf(p3.x, kq[12], dot); dot = fmaf(p3.y, kq[13], dot);
        dot = fmaf(p3.z, kq[14], dot); dot = fmaf(p3.w, kq[15], dot);
        sc[c] = Arow[j] * dot * INV_SQRT_D;
        const float e = E[j] - Ei;
        ed[c] = e;
        sg[c] = 1.0f / (1.0f + __expf(-KSHARP * e));
    }

    // ---- wave-local softmax (no LDS, no barriers) ----
    float m = sc[0];
    #pragma unroll
    for (int c = 1; c < 8; ++c) m = fmaxf(m, sc[c]);
    #pragma unroll
    for (int off = 32; off >= 1; off >>= 1) m = fmaxf(m, __shfl_xor(m, off));
    float s = 0.f;
    #pragma unroll
    for (int c = 0; c < 8; ++c) { sc[c] = __expf(sc[c] - m); s += sc[c]; }
    #pragma unroll
    for (int off = 32; off >= 1; off >>= 1) s += __shfl_xor(s, off);
    const float inv = 1.0f / s;

    // ---- publish packed per-j coefficients to this wave's LDS region ----
    #pragma unroll
    for (int c = 0; c < 8; ++c) {
        const int j = c * 64 + lane;
        const float w = sc[c] * inv;
        sP[wave][j] = make_float4(w, w * ed[c], sg[c], 0.f);
    }
    __syncthreads();   // only barrier: make wave's LDS writes visible across its lanes

    // ---- contraction: each half-wave covers 256 j, d = lane&31 ----
    const float* hlb = hl + (size_t)b * NN * 64;
    const int j0 = half * 256;
    float acc = 0.f;
    #pragma unroll 4
    for (int jj = 0; jj < 256; ++jj) {
        const int j = j0 + jj;
        const float4 P = sP[wave][j];
        const float2 hj = *(const float2*)(hlb + (size_t)j * 64 + 2 * d);
        const float drift = fmaf(P.x * bd, hj.y - Li, P.y);
        const float wh    = fmaf(P.z, hj.x - hi, hi);
        acc = fmaf(drift, wh, acc);
    }
    acc += __shfl_xor(acc, 32);
    if (lane < 32) out[(size_t)row * ND + d] = acc;
}

extern "C" void kernel_launch(void* const* d_in, const int* in_sizes, int n_in,
                              void* d_out, int out_size, void* d_ws, size_t ws_size,
                              hipStream_t stream) {
    // input order: t, h, pe, E, A, Wk, bk, Wq, bq, beta
    const float* h    = (const float*)d_in[1];
    const float* pe   = (const float*)d_in[2];
    const float* E    = (const float*)d_in[3];
    const float* A    = (const float*)d_in[4];
    const float* Wk   = (const float*)d_in[5];
    const float* bk   = (const float*)d_in[6];
    const float* Wq   = (const float*)d_in[7];
    const float* bq   = (const float*)d_in[8];
    const float* beta = (const float*)d_in[9];
    float* out = (float*)d_out;

    float* hl  = (float*)d_ws;
    float* kwq = hl + HL_FLOATS;

    prep_kernel<<<NB * NN / 4, 256, 0, stream>>>(h, pe, Wk, bk, Wq, bq, hl, kwq);
    fpg_kernel<<<NB * NN / 4, 256, 0, stream>>>(pe, E, A, beta, hl, kwq, out);
}

// Round 4
// 31.033 us; speedup vs baseline: 1.1362x; 1.1362x over previous
//
#include <hip/hip_runtime.h>
#include <math.h>

constexpr int NB = 4;
constexpr int NN = 512;
constexpr int ND = 32;
constexpr int NPE = 16;
constexpr float INV_SQRT_D = 0.17677669529663687f; // 1/sqrt(32)
constexpr float KSHARP = 10.0f;

// ---------- Prep: pack {h, log(h+1e-8)} as interleaved float2 ----------
__global__ __launch_bounds__(256) void prep_kernel(const float* __restrict__ h,
                                                   float2* __restrict__ hl, int n) {
    int idx = blockIdx.x * 256 + threadIdx.x;
    if (idx < n) {
        float hv = h[idx];
        hl[idx] = make_float2(hv, logf(hv + 1e-8f));
    }
}

// ---------- Main: one block (4 waves) per output row ----------
__global__ __launch_bounds__(256) void fpg_kernel(
    const float* __restrict__ pe,
    const float* __restrict__ E,
    const float* __restrict__ A,
    const float* __restrict__ Wk,
    const float* __restrict__ bk,
    const float* __restrict__ Wq,
    const float* __restrict__ bq,
    const float* __restrict__ beta,
    const float2* __restrict__ hl,
    float* __restrict__ out)
{
    const int row  = blockIdx.x;          // [0, B*N)
    const int b    = row >> 9;
    const int i    = row & (NN - 1);
    const int t    = threadIdx.x;
    const int lane = t & 63;
    const int wv   = t >> 6;

    __shared__ __align__(16) float sK[ND];
    __shared__ __align__(16) float sKWq[20];   // 16 KWq + C0 (idx 16)
    __shared__ float4 sP[NN];                  // {W, W*Ed, sig, 0} — 8 KB
    __shared__ float sRedM[4];
    __shared__ float sRedS[4];
    __shared__ float sAcc[8][ND];

    // ---- Phase A: K_i = pe_i @ Wk + bk ----
    if (t < ND) {
        const float* pe_i = pe + (size_t)row * NPE;
        float k = bk[t];
        #pragma unroll
        for (int p = 0; p < NPE; ++p) k = fmaf(pe_i[p], Wk[p * ND + t], k);
        sK[t] = k;
    }
    __syncthreads();
    // ---- Phase A2: KWq[p] = K_i . Wq[p,:], C0 = K_i . bq ----
    if (t < 17) {
        const float* wrow = (t < 16) ? (Wq + t * ND) : bq;
        float acc = 0.f;
        #pragma unroll
        for (int d = 0; d < ND; ++d) acc = fmaf(sK[d], wrow[d], acc);
        sKWq[t] = acc;
    }
    __syncthreads();

    // preload KWq into registers (broadcast reads)
    float kq[17];
    #pragma unroll
    for (int p = 0; p < 17; ++p) kq[p] = sKWq[p];

    // ---- Phase B: 2 j per thread — score, E-diff, sigmoid ----
    const float Ei = E[i];
    const float* pe_b = pe + (size_t)b * NN * NPE;
    const float* Arow = A + (size_t)i * NN;
    float sc[2], ed[2], sg[2];
    #pragma unroll
    for (int c = 0; c < 2; ++c) {
        const int j = t + c * 256;
        const float4* pj = (const float4*)(pe_b + (size_t)j * NPE);
        const float4 p0 = pj[0], p1 = pj[1], p2 = pj[2], p3 = pj[3];
        float dot = kq[16];
        dot = fmaf(p0.x, kq[0],  dot); dot = fmaf(p0.y, kq[1],  dot);
        dot = fmaf(p0.z, kq[2],  dot); dot = fmaf(p0.w, kq[3],  dot);
        dot = fmaf(p1.x, kq[4],  dot); dot = fmaf(p1.y, kq[5],  dot);
        dot = fmaf(p1.z, kq[6],  dot); dot = fmaf(p1.w, kq[7],  dot);
        dot = fmaf(p2.x, kq[8],  dot); dot = fmaf(p2.y, kq[9],  dot);
        dot = fmaf(p2.z, kq[10], dot); dot = fmaf(p2.w, kq[11], dot);
        dot = fmaf(p3.x, kq[12], dot); dot = fmaf(p3.y, kq[13], dot);
        dot = fmaf(p3.z, kq[14], dot); dot = fmaf(p3.w, kq[15], dot);
        sc[c] = Arow[j] * dot * INV_SQRT_D;
        const float e = E[j] - Ei;
        ed[c] = e;
        sg[c] = 1.0f / (1.0f + __expf(-KSHARP * e));
    }

    // ---- Phase C: block softmax (wave shfl + 4-entry LDS combine) ----
    float m = fmaxf(sc[0], sc[1]);
    #pragma unroll
    for (int off = 32; off >= 1; off >>= 1) m = fmaxf(m, __shfl_xor(m, off));
    if (lane == 0) sRedM[wv] = m;
    __syncthreads();
    const float M = fmaxf(fmaxf(sRedM[0], sRedM[1]), fmaxf(sRedM[2], sRedM[3]));
    const float e0 = __expf(sc[0] - M);
    const float e1 = __expf(sc[1] - M);
    float s = e0 + e1;
    #pragma unroll
    for (int off = 32; off >= 1; off >>= 1) s += __shfl_xor(s, off);
    if (lane == 0) sRedS[wv] = s;
    __syncthreads();
    const float S = sRedS[0] + sRedS[1] + sRedS[2] + sRedS[3];
    const float inv = 1.0f / S;

    // ---- Phase D: publish packed per-j coefficients ----
    {
        const float w0 = e0 * inv, w1 = e1 * inv;
        sP[t]       = make_float4(w0, w0 * ed[0], sg[0], 0.f);
        sP[t + 256] = make_float4(w1, w1 * ed[1], sg[1], 0.f);
    }
    __syncthreads();

    // ---- Phase E: contraction, d = t&31, 8 j-groups ----
    const int d = t & 31, g = t >> 5;
    const float2 hli = hl[(size_t)row * ND + d];
    const float hi = hli.x, Li = hli.y;
    const float bd = beta[d];
    const float2* hlb = hl + (size_t)b * NN * ND;
    float acc = 0.f;
    #pragma unroll 8
    for (int jj = 0; jj < 64; ++jj) {
        const int j = g + (jj << 3);
        const float4 P = sP[j];
        const float2 hj = hlb[(size_t)j * ND + d];
        const float drift = fmaf(P.x * bd, hj.y - Li, P.y);
        const float wh    = fmaf(P.z, hj.x - hi, hi);
        acc = fmaf(drift, wh, acc);
    }
    sAcc[g][d] = acc;
    __syncthreads();
    if (t < ND) {
        float r0 = sAcc[0][t] + sAcc[1][t];
        float r1 = sAcc[2][t] + sAcc[3][t];
        float r2 = sAcc[4][t] + sAcc[5][t];
        float r3 = sAcc[6][t] + sAcc[7][t];
        out[(size_t)row * ND + t] = (r0 + r1) + (r2 + r3);
    }
}

extern "C" void kernel_launch(void* const* d_in, const int* in_sizes, int n_in,
                              void* d_out, int out_size, void* d_ws, size_t ws_size,
                              hipStream_t stream) {
    // input order: t, h, pe, E, A, Wk, bk, Wq, bq, beta
    const float* h    = (const float*)d_in[1];
    const float* pe   = (const float*)d_in[2];
    const float* E    = (const float*)d_in[3];
    const float* A    = (const float*)d_in[4];
    const float* Wk   = (const float*)d_in[5];
    const float* bk   = (const float*)d_in[6];
    const float* Wq   = (const float*)d_in[7];
    const float* bq   = (const float*)d_in[8];
    const float* beta = (const float*)d_in[9];
    float* out = (float*)d_out;
    float2* hl = (float2*)d_ws;   // B*N*ND float2 = 512 KB

    const int n = NB * NN * ND;   // 65536
    prep_kernel<<<(n + 255) / 256, 256, 0, stream>>>(h, hl, n);
    fpg_kernel<<<NB * NN, 256, 0, stream>>>(pe, E, A, Wk, bk, Wq, bq, beta, hl, out);
}

// Round 5
// 17.024 us; speedup vs baseline: 2.0713x; 1.8229x over previous
//
#include <hip/hip_runtime.h>
#include <math.h>

constexpr int NB = 4;
constexpr int NN = 512;
constexpr int ND = 32;
constexpr int NPE = 16;
constexpr float INV_SQRT_D = 0.17677669529663687f; // 1/sqrt(32)
constexpr float KSHARP = 10.0f;
constexpr float LN2 = 0.69314718055994531f;

// Single fused kernel. TI=4 rows per block, 512 threads (8 waves), 512 blocks.
// out[i,d] = A2 + b2*(A4 + hi*A3 - L2i*A5) + hi*(S1 - b2*L2i*S3)
//   where (per (i,j)): c2=W*e*sig, c3=W*(1-sig), c4=W*sig, e=Ej-Ei,
//   A2=sum_j c2*hj, A3=sum_j c3*log2(hj+eps), A4=sum_j c4*hj*log2(hj+eps),
//   A5=sum_j c4*hj, S1=sum_j W*e*(1-sig), S3=sum_j c3, b2=beta_d*ln2.
__global__ __launch_bounds__(512, 4) void fpg_kernel(
    const float* __restrict__ h,
    const float* __restrict__ pe,
    const float* __restrict__ E,
    const float* __restrict__ A,
    const float* __restrict__ Wk,
    const float* __restrict__ bk,
    const float* __restrict__ Wq,
    const float* __restrict__ bq,
    const float* __restrict__ beta,
    float* __restrict__ out)
{
    const int blk = blockIdx.x;          // 512 blocks = 4 batches x 128 tiles
    const int b   = blk >> 7;
    const int i0  = (blk & 127) << 2;    // 4 rows per block
    const int t   = threadIdx.x;

    __shared__ __align__(16) float sK[4][ND];
    __shared__ float sKWq[4][20];              // 17 used
    __shared__ __align__(16) float sCoef[NN][3][4];  // [j][{c2,c3,c4}][row] 24 KB
    __shared__ float sPart[4][2][4];           // [row][wave-half][max, s0, s1, s2]
    __shared__ float sS1[4], sS3[4];
    __shared__ float sRed[16][4][ND];          // 8 KB partial outputs

    const float* h_b  = h  + (size_t)b * NN * ND;
    const float* pe_b = pe + (size_t)b * NN * NPE;

    // ---- Phase A: K rows = pe_i @ Wk + bk ----
    if (t < 128) {
        const int r = t >> 5, d = t & 31;
        const float* pe_i = pe_b + (size_t)(i0 + r) * NPE;
        float k = bk[d];
        #pragma unroll
        for (int p = 0; p < NPE; ++p) k = fmaf(pe_i[p], Wk[p * ND + d], k);
        sK[r][d] = k;
    }
    __syncthreads();

    // ---- Phase A2: KWq[r][p] = K_r . Wq[p,:]; [16] = K_r . bq ----
    if (t < 128) {
        const int r = t >> 5, q = t & 31;
        if (q < 17) {
            const float* wrow = (q < 16) ? (Wq + q * ND) : bq;
            float acc = 0.f;
            #pragma unroll
            for (int d = 0; d < ND; ++d) acc = fmaf(sK[r][d], wrow[d], acc);
            sKWq[r][q] = acc;
        }
    }
    __syncthreads();

    // ---- Phase B: row r = t>>7 (2 waves per row), 4 j per thread ----
    const int r    = t >> 7;
    const int jj   = t & 127;
    const int i    = i0 + r;
    const int lane = t & 63;
    const int wh   = (t >> 6) & 1;   // wave-half within row-group

    float kq[17];
    #pragma unroll
    for (int p = 0; p < 17; ++p) kq[p] = sKWq[r][p];
    const float Ei = E[i];
    const float* Arow = A + (size_t)i * NN;

    float sc[4], ed[4], sg[4];
    #pragma unroll
    for (int k = 0; k < 4; ++k) {
        const int j = jj + (k << 7);
        const float4* pj = (const float4*)(pe_b + (size_t)j * NPE);
        const float4 p0 = pj[0], p1 = pj[1], p2 = pj[2], p3 = pj[3];
        float dot = kq[16];
        dot = fmaf(p0.x, kq[0],  dot); dot = fmaf(p0.y, kq[1],  dot);
        dot = fmaf(p0.z, kq[2],  dot); dot = fmaf(p0.w, kq[3],  dot);
        dot = fmaf(p1.x, kq[4],  dot); dot = fmaf(p1.y, kq[5],  dot);
        dot = fmaf(p1.z, kq[6],  dot); dot = fmaf(p1.w, kq[7],  dot);
        dot = fmaf(p2.x, kq[8],  dot); dot = fmaf(p2.y, kq[9],  dot);
        dot = fmaf(p2.z, kq[10], dot); dot = fmaf(p2.w, kq[11], dot);
        dot = fmaf(p3.x, kq[12], dot); dot = fmaf(p3.y, kq[13], dot);
        dot = fmaf(p3.z, kq[14], dot); dot = fmaf(p3.w, kq[15], dot);
        sc[k] = Arow[j] * dot * INV_SQRT_D;
        const float e = E[j] - Ei;
        ed[k] = e;
        sg[k] = 1.0f / (1.0f + __expf(-KSHARP * e));
    }

    // ---- Phase C: per-row max / sums over this row's 2 waves ----
    float m = fmaxf(fmaxf(sc[0], sc[1]), fmaxf(sc[2], sc[3]));
    #pragma unroll
    for (int off = 32; off >= 1; off >>= 1) m = fmaxf(m, __shfl_xor(m, off));
    if (lane == 0) sPart[r][wh][0] = m;
    __syncthreads();
    const float M = fmaxf(sPart[r][0][0], sPart[r][1][0]);

    float eh[4];
    float s0 = 0.f, s1 = 0.f, s2 = 0.f;
    #pragma unroll
    for (int k = 0; k < 4; ++k) {
        eh[k] = __expf(sc[k] - M);
        const float om = 1.0f - sg[k];
        s0 += eh[k];
        s1 += eh[k] * ed[k] * om;
        s2 += eh[k] * om;
    }
    #pragma unroll
    for (int off = 32; off >= 1; off >>= 1) {
        s0 += __shfl_xor(s0, off);
        s1 += __shfl_xor(s1, off);
        s2 += __shfl_xor(s2, off);
    }
    if (lane == 0) { sPart[r][wh][1] = s0; sPart[r][wh][2] = s1; sPart[r][wh][3] = s2; }
    __syncthreads();
    const float S   = sPart[r][0][1] + sPart[r][1][1];
    const float inv = 1.0f / S;
    if ((t & 127) == 0) {
        sS1[r] = (sPart[r][0][2] + sPart[r][1][2]) * inv;   // sum W*e*(1-sig)
        sS3[r] = (sPart[r][0][3] + sPart[r][1][3]) * inv;   // sum W*(1-sig)
    }

    // ---- Phase D: publish c2,c3,c4 (component r of each float4) ----
    #pragma unroll
    for (int k = 0; k < 4; ++k) {
        const int j = jj + (k << 7);
        const float w  = eh[k] * inv;
        const float c4 = w * sg[k];
        const float c3 = w - c4;
        const float c2 = w * ed[k] * sg[k];
        sCoef[j][0][r] = c2;
        sCoef[j][1][r] = c3;
        sCoef[j][2][r] = c4;
    }
    __syncthreads();

    // ---- Phase E: d = t&31, 16 j-groups; 4 accumulators x 4 rows ----
    const int d = t & 31, g = t >> 5;
    const float b2 = beta[d] * LN2;
    float vA2[4] = {0,0,0,0}, vA3[4] = {0,0,0,0};
    float vA4[4] = {0,0,0,0}, vA5[4] = {0,0,0,0};
    #pragma unroll 4
    for (int q = 0; q < 32; ++q) {
        const int j = (q << 4) + g;
        const float4 C2 = *(const float4*)sCoef[j][0];
        const float4 C3 = *(const float4*)sCoef[j][1];
        const float4 C4 = *(const float4*)sCoef[j][2];
        const float hv = h_b[(size_t)j * ND + d];
        const float L2 = __log2f(hv + 1e-8f);
        const float hL = hv * L2;
        vA2[0] = fmaf(C2.x, hv, vA2[0]); vA2[1] = fmaf(C2.y, hv, vA2[1]);
        vA2[2] = fmaf(C2.z, hv, vA2[2]); vA2[3] = fmaf(C2.w, hv, vA2[3]);
        vA3[0] = fmaf(C3.x, L2, vA3[0]); vA3[1] = fmaf(C3.y, L2, vA3[1]);
        vA3[2] = fmaf(C3.z, L2, vA3[2]); vA3[3] = fmaf(C3.w, L2, vA3[3]);
        vA4[0] = fmaf(C4.x, hL, vA4[0]); vA4[1] = fmaf(C4.y, hL, vA4[1]);
        vA4[2] = fmaf(C4.z, hL, vA4[2]); vA4[3] = fmaf(C4.w, hL, vA4[3]);
        vA5[0] = fmaf(C4.x, hv, vA5[0]); vA5[1] = fmaf(C4.y, hv, vA5[1]);
        vA5[2] = fmaf(C4.z, hv, vA5[2]); vA5[3] = fmaf(C4.w, hv, vA5[3]);
    }
    // per-group partial (linear in the A's; constants folded after reduce)
    #pragma unroll
    for (int rr = 0; rr < 4; ++rr) {
        const float hi  = h_b[(size_t)(i0 + rr) * ND + d];
        const float L2i = __log2f(hi + 1e-8f);
        const float p = vA2[rr] + b2 * (vA4[rr] + hi * vA3[rr] - L2i * vA5[rr]);
        sRed[g][rr][d] = p;
    }
    __syncthreads();

    // ---- Final reduce + constant term + store ----
    if (t < 128) {
        const int rr = t >> 5, dd = t & 31;
        float sum = 0.f;
        #pragma unroll
        for (int g2 = 0; g2 < 16; ++g2) sum += sRed[g2][rr][dd];
        const float hi  = h_b[(size_t)(i0 + rr) * ND + dd];
        const float L2i = __log2f(hi + 1e-8f);
        const float b2d = beta[dd] * LN2;
        out[(size_t)(b * NN + i0 + rr) * ND + dd] =
            sum + hi * (sS1[rr] - b2d * L2i * sS3[rr]);
    }
}

extern "C" void kernel_launch(void* const* d_in, const int* in_sizes, int n_in,
                              void* d_out, int out_size, void* d_ws, size_t ws_size,
                              hipStream_t stream) {
    // input order: t, h, pe, E, A, Wk, bk, Wq, bq, beta
    const float* h    = (const float*)d_in[1];
    const float* pe   = (const float*)d_in[2];
    const float* E    = (const float*)d_in[3];
    const float* A    = (const float*)d_in[4];
    const float* Wk   = (const float*)d_in[5];
    const float* bk   = (const float*)d_in[6];
    const float* Wq   = (const float*)d_in[7];
    const float* bq   = (const float*)d_in[8];
    const float* beta = (const float*)d_in[9];
    float* out = (float*)d_out;

    fpg_kernel<<<NB * NN / 4, 512, 0, stream>>>(pe ? h : h, pe, E, A, Wk, bk, Wq, bq, beta, out);
}